// Round 1
// 809.544 us; speedup vs baseline: 1.4825x; 1.4825x over previous
//
#include <hip/hip_runtime.h>
#include <stdint.h>

#define TOK   8192        // 8 frames * 1024 tokens
#define DIM   640
#define HEADS 8
#define HD    80
#define SEQ   1024
#define CROSS 768
#define ETOK  616         // 8 * 77 encoder tokens
#define FFI   2560        // FF inner (half of 5120 proj)
#define SCALE 0.11180339887498949f

typedef unsigned short u16;
typedef unsigned int   u32;

using bf8   = __attribute__((ext_vector_type(8))) short;   // 8 bf16 (4 VGPRs)
using f32x4 = __attribute__((ext_vector_type(4))) float;   // MFMA C/D

struct __align__(16) U4 { u32 x, y, z, w; };

__device__ __forceinline__ float bf2f(u16 u){
  union { u32 i; float f; } v; v.i = ((u32)u) << 16; return v.f;
}
__device__ __forceinline__ u16 f2bf(float f){
  union { float f; u32 i; } v; v.f = f;
  u32 r = v.i + 0x7fffu + ((v.i >> 16) & 1u);
  return (u16)(r >> 16);
}
__device__ __forceinline__ float gelu_t(float x){
  float y = 0.7978845608028654f * (x + 0.044715f * x * x * x);
  float e = __expf(2.f * y);
  return 0.5f * x * (2.f - 2.f / (e + 1.f));
}

// async global->LDS, 16B per lane; LDS dest is wave-uniform base + lane*16
__device__ __forceinline__ void gl2lds16(const u16* g, u16* l){
  __builtin_amdgcn_global_load_lds(
      (const __attribute__((address_space(1))) void*)g,
      (__attribute__((address_space(3))) void*)l, 16, 0, 0);
}

// ---------------- fp32 -> bf16 mirrors -------------------------------------
struct CvtJob  { const float* s; u16* d; int n; };
struct CvtJobs { CvtJob j[11]; };
__global__ __launch_bounds__(256) void cvt_all(CvtJobs jobs)
{
  const CvtJob jb = jobs.j[blockIdx.y];
  for (long i = (long)blockIdx.x*256 + threadIdx.x; i < jb.n; i += (long)gridDim.x*256)
    jb.d[i] = f2bf(jb.s[i]);
}

// ---------------- tiled weight transposes (fp32 src -> bf16 dst) -----------
// All job dims are multiples of 64. 64x64 tile via LDS, coalesced both sides.
struct TJob  { const float* s; u16* d; int R, C, srcLd, dstLd; };
struct TJobs { TJob j[10]; };
__global__ __launch_bounds__(256) void transpose_tiled(TJobs jobs)
{
  const TJob jb = jobs.j[blockIdx.y];
  const int tilesC = jb.C >> 6;
  const int nt = (jb.R >> 6) * tilesC;
  if ((int)blockIdx.x >= nt) return;
  const int tr = (blockIdx.x / tilesC) << 6, tc = (blockIdx.x % tilesC) << 6;
  __shared__ u16 t[64][65];
  const int tid = threadIdx.x;
  const int rr = tid >> 3, c8 = (tid & 7) * 8;
  #pragma unroll
  for (int p = 0; p < 2; ++p){
    const int r = rr + p*32;
    const float* s = &jb.s[(long)(tr + r)*jb.srcLd + tc + c8];
    #pragma unroll
    for (int j = 0; j < 8; ++j) t[r][c8 + j] = f2bf(s[j]);
  }
  __syncthreads();
  #pragma unroll
  for (int p = 0; p < 2; ++p){
    const int c = rr + p*32;
    u16 tmp[8];
    #pragma unroll
    for (int j = 0; j < 8; ++j) tmp[j] = t[c8 + j][c];
    *(U4*)&jb.d[(long)(tc + c)*jb.dstLd + tr + c8] = *(U4*)tmp;
  }
}

// ---------------- tiled bf16 transpose (v1T): R,C multiples of 64 ----------
__global__ __launch_bounds__(256) void transpose_tile(
    const u16* __restrict__ src, u16* __restrict__ dst,
    int srcLd, int dstLd)
{
  __shared__ u16 t[64][65];
  const int tr = blockIdx.y << 6, tc = blockIdx.x << 6;
  const int tid = threadIdx.x;
  const int rr = tid >> 3, c8 = (tid & 7) * 8;
  #pragma unroll
  for (int p = 0; p < 2; ++p){
    const int r = rr + p*32;
    U4 v = *(const U4*)&src[(long)(tr + r)*srcLd + tc + c8];
    const u16* pv = (const u16*)&v;
    #pragma unroll
    for (int j = 0; j < 8; ++j) t[r][c8 + j] = pv[j];
  }
  __syncthreads();
  #pragma unroll
  for (int p = 0; p < 2; ++p){
    const int c = rr + p*32;
    u16 tmp[8];
    #pragma unroll
    for (int j = 0; j < 8; ++j) tmp[j] = t[c8 + j][c];
    *(U4*)&dst[(long)(tc + c)*dstLd + tr + c8] = *(U4*)tmp;
  }
}

// v2 transpose with per-batch padding 77->80 (16B-aligned attention loads)
__global__ __launch_bounds__(256) void transpose_v2(
    const u16* __restrict__ src, u16* __restrict__ dst)
{
  int idx = blockIdx.x*256 + threadIdx.x;
  if (idx >= ETOK*DIM) return;
  int rr = idx / DIM, d = idx - rr*DIM;
  int g = rr / 77, j = rr - g*77;
  dst[(long)d*DIM + g*80 + j] = src[(long)rr*(2*DIM) + DIM + d];
}

// ---------------- LayerNorm: one block per row (src fp32 or bf16) ----------
__global__ __launch_bounds__(256) void ln_k(
    const void* __restrict__ src, const u16* __restrict__ w,
    const u16* __restrict__ b, u16* __restrict__ dst, int srcf32)
{
  __shared__ float xr[DIM];
  __shared__ float red[256];
  const int tid = threadIdx.x;
  const long row = blockIdx.x;
  float ls = 0.f;
  for (int i = tid; i < DIM; i += 256){
    float v = srcf32 ? ((const float*)src)[row*DIM + i]
                     : bf2f(((const u16*)src)[row*DIM + i]);
    xr[i] = v; ls += v;
  }
  red[tid] = ls; __syncthreads();
  for (int o = 128; o > 0; o >>= 1){ if (tid < o) red[tid] += red[tid+o]; __syncthreads(); }
  const float mean = red[0] * (1.f/DIM);
  __syncthreads();
  float lq = 0.f;
  for (int i = tid; i < DIM; i += 256){ float d = xr[i] - mean; lq += d*d; }
  red[tid] = lq; __syncthreads();
  for (int o = 128; o > 0; o >>= 1){ if (tid < o) red[tid] += red[tid+o]; __syncthreads(); }
  const float var = red[0] * (1.f/DIM);
  const float rs = rsqrtf(var + 1e-5f);
  u16* q = dst + row*DIM;
  for (int i = tid; i < DIM; i += 256)
    q[i] = f2bf((xr[i] - mean)*rs*bf2f(w[i]) + bf2f(b[i]));
}

// ---------------- MFMA GEMM, templated N-tile ------------------------------
// C[M,N] = A[M,K] @ BT[N,K]^T (+bias +residual). Block tile 128 x BN, BK=32,
// 4 waves each 64 x BN/2. Staging via global_load_lds width=16: per-lane
// global address pre-permuted to fragment order (row=lane&15, kq=lane>>4),
// LDS chunk is lane-linear (lane*16B) -> frag ds_read_b128 conflict-free,
// zero ds_writes, one barrier per K-step, double-buffered.
template<int BN>
__global__ __launch_bounds__(256) void gemm_bt(
    const u16* __restrict__ A, const u16* __restrict__ BT, void* __restrict__ C,
    int M, int N, int K, int lda, int ldb, int ldc,
    const u16* __restrict__ bias, const void* __restrict__ res, int ldr,
    int resf32, int outf32)
{
  constexpr int NT  = BN/32;        // n-subtiles per wave
  constexpr int BCH = BN/16;        // B chunks per K-step
  constexpr int BPW = BCH/4;        // B chunks per wave
  __shared__ __align__(16) u16 sA[2][8*512];
  __shared__ __align__(16) u16 sB[2][BCH*512];
  const int tid  = threadIdx.x;
  const int wave = tid >> 6, lane = tid & 63;
  const int quad = lane >> 4, l16 = lane & 15;
  const int m0 = blockIdx.y * 128, n0 = blockIdx.x * BN;
  const int wm = (wave >> 1) * 64, wn = (wave & 1) * (BN/2);
  const int srow = lane & 15;       // row within 16-row chunk
  const int scol = (lane >> 4) * 8; // k offset within 32

  long aoff[2];
  #pragma unroll
  for (int i = 0; i < 2; ++i){
    int r = m0 + (wave*2 + i)*16 + srow;
    r = r < M ? r : M - 1;          // clamp (M edge)
    aoff[i] = (long)r*lda + scol;
  }
  long boff[BPW];
  #pragma unroll
  for (int i = 0; i < BPW; ++i){
    int r = n0 + (wave*BPW + i)*16 + srow;
    boff[i] = (long)r*ldb + scol;
  }

  f32x4 acc[4][NT] = {};
  #pragma unroll
  for (int i = 0; i < 2; ++i)   gl2lds16(&A[aoff[i]],  &sA[0][(wave*2 + i)*512]);
  #pragma unroll
  for (int i = 0; i < BPW; ++i) gl2lds16(&BT[boff[i]], &sB[0][(wave*BPW + i)*512]);
  __syncthreads();

  int cur = 0;
  for (int k0 = 0; ; ){
    const int kn = k0 + 32;
    if (kn < K){
      #pragma unroll
      for (int i = 0; i < 2; ++i)   gl2lds16(&A[aoff[i] + kn],  &sA[cur^1][(wave*2 + i)*512]);
      #pragma unroll
      for (int i = 0; i < BPW; ++i) gl2lds16(&BT[boff[i] + kn], &sB[cur^1][(wave*BPW + i)*512]);
    }
    bf8 a[4], b[NT];
    #pragma unroll
    for (int mt = 0; mt < 4; ++mt)  a[mt] = *(const bf8*)&sA[cur][((wm>>4) + mt)*512 + lane*8];
    #pragma unroll
    for (int nt = 0; nt < NT; ++nt) b[nt] = *(const bf8*)&sB[cur][((wn>>4) + nt)*512 + lane*8];
    #pragma unroll
    for (int mt = 0; mt < 4; ++mt)
      #pragma unroll
      for (int nt = 0; nt < NT; ++nt)
        acc[mt][nt] = __builtin_amdgcn_mfma_f32_16x16x32_bf16(a[mt], b[nt], acc[mt][nt], 0, 0, 0);
    k0 = kn;
    if (k0 >= K) break;
    __syncthreads();                // drains vmcnt: next-iter stage complete
    cur ^= 1;
  }
  #pragma unroll
  for (int mt = 0; mt < 4; ++mt){
    const int rl = wm + mt*16 + quad*4;
    #pragma unroll
    for (int nt = 0; nt < NT; ++nt){
      const int col = n0 + wn + nt*16 + l16;
      float bv = bias ? bf2f(bias[col]) : 0.f;
      #pragma unroll
      for (int r = 0; r < 4; ++r){
        int row = m0 + rl + r;
        if (row < M){
          float v = acc[mt][nt][r] + bv;
          if (res) v += resf32 ? ((const float*)res)[(long)row*ldr + col]
                               : bf2f(((const u16*)res)[(long)row*ldr + col]);
          if (outf32) ((float*)C)[(long)row*ldc + col] = v;
          else        ((u16*)C) [(long)row*ldc + col] = f2bf(v);
        }
      }
    }
  }
}

// ---------------- fused GEGLU GEMM, 128x64 tile ----------------------------
// out = (x@W1h + bh) * gelu(x@W1g + bg); W1T rows [n]=h, [2560+n]=gate
__global__ __launch_bounds__(256) void gemm_geglu(
    const u16* __restrict__ A, const u16* __restrict__ W, u16* __restrict__ C,
    const u16* __restrict__ bias)
{
  __shared__ __align__(16) u16 sA[2][8*512];
  __shared__ __align__(16) u16 sH[2][4*512];
  __shared__ __align__(16) u16 sG[2][4*512];
  const int tid  = threadIdx.x;
  const int wave = tid >> 6, lane = tid & 63;
  const int quad = lane >> 4, l16 = lane & 15;
  const int m0 = blockIdx.y * 128, n0 = blockIdx.x * 64;
  const int wm = (wave >> 1) * 64, wn = (wave & 1) * 32;
  const int srow = lane & 15;
  const int scol = (lane >> 4) * 8;

  long aoff[2];
  #pragma unroll
  for (int i = 0; i < 2; ++i)
    aoff[i] = (long)(m0 + (wave*2 + i)*16 + srow)*DIM + scol;
  const long hoff = (long)(n0 + wave*16 + srow)*DIM + scol;
  const long goff = (long)(FFI + n0 + wave*16 + srow)*DIM + scol;

  f32x4 ah[4][2] = {}, ag[4][2] = {};
  #pragma unroll
  for (int i = 0; i < 2; ++i) gl2lds16(&A[aoff[i]], &sA[0][(wave*2 + i)*512]);
  gl2lds16(&W[hoff], &sH[0][wave*512]);
  gl2lds16(&W[goff], &sG[0][wave*512]);
  __syncthreads();

  int cur = 0;
  for (int k0 = 0; ; ){
    const int kn = k0 + 32;
    if (kn < DIM){
      #pragma unroll
      for (int i = 0; i < 2; ++i) gl2lds16(&A[aoff[i] + kn], &sA[cur^1][(wave*2 + i)*512]);
      gl2lds16(&W[hoff + kn], &sH[cur^1][wave*512]);
      gl2lds16(&W[goff + kn], &sG[cur^1][wave*512]);
    }
    bf8 a[4];
    #pragma unroll
    for (int mt = 0; mt < 4; ++mt) a[mt] = *(const bf8*)&sA[cur][((wm>>4) + mt)*512 + lane*8];
    #pragma unroll
    for (int nt = 0; nt < 2; ++nt){
      bf8 bh = *(const bf8*)&sH[cur][((wn>>4) + nt)*512 + lane*8];
      bf8 bg = *(const bf8*)&sG[cur][((wn>>4) + nt)*512 + lane*8];
      #pragma unroll
      for (int mt = 0; mt < 4; ++mt){
        ah[mt][nt] = __builtin_amdgcn_mfma_f32_16x16x32_bf16(a[mt], bh, ah[mt][nt], 0, 0, 0);
        ag[mt][nt] = __builtin_amdgcn_mfma_f32_16x16x32_bf16(a[mt], bg, ag[mt][nt], 0, 0, 0);
      }
    }
    k0 = kn;
    if (k0 >= DIM) break;
    __syncthreads();
    cur ^= 1;
  }
  #pragma unroll
  for (int mt = 0; mt < 4; ++mt){
    const int rl = wm + mt*16 + quad*4;
    #pragma unroll
    for (int nt = 0; nt < 2; ++nt){
      const int col = n0 + wn + nt*16 + l16;
      const float bh = bf2f(bias[col]);
      const float bg = bf2f(bias[FFI + col]);
      #pragma unroll
      for (int r = 0; r < 4; ++r){
        int row = m0 + rl + r;
        float h = ah[mt][nt][r] + bh;
        float g = ag[mt][nt][r] + bg;
        C[(long)row*FFI + col] = f2bf(h * gelu_t(g));
      }
    }
  }
}

// ---------------- MFMA flash attention (validated R7) ----------------------
template<int MODE>
__global__ __launch_bounds__(256) void attn_k(
    const u16* __restrict__ qbuf, const u16* __restrict__ kbuf,
    const u16* __restrict__ vT, u16* __restrict__ out)
{
  constexpr int QLD  = MODE ? DIM      : 3*DIM;
  constexpr int KLD  = MODE ? 2*DIM    : 3*DIM;
  constexpr int KCOL = MODE ? 0        : DIM;
  constexpr int VLD  = MODE ? DIM      : TOK;
  constexpr int NK   = MODE ? 77       : 2*SEQ;
  constexpr int NCH  = MODE ? 3        : 64;

  const int qt = blockIdx.x, h = blockIdx.y, g = blockIdx.z;
  const int tid = threadIdx.x, wave = tid >> 6, lane = tid & 63;
  const int quad = lane >> 4, l16 = lane & 15;

  __shared__ __align__(16) u16 Qs[64*96];
  __shared__ __align__(16) u16 Ks[32*96];
  __shared__ __align__(16) u16 Vs[80*32];
  __shared__ __align__(16) u16 Ps[4][16*32];

  const int qrow0 = g*SEQ + qt*64;
  for (int v = tid; v < 640; v += 256){
    int r = v/10, c8 = (v - r*10)*8;
    *(U4*)&Qs[r*96 + c8] = *(const U4*)&qbuf[(long)(qrow0 + r)*QLD + h*HD + c8];
  }
  for (int v = tid; v < 128; v += 256){
    U4 z = {0,0,0,0};
    *(U4*)&Qs[(v>>1)*96 + 80 + (v&1)*8] = z;
  }
  for (int v = tid; v < 64; v += 256){
    U4 z = {0,0,0,0};
    *(U4*)&Ks[(v>>1)*96 + 80 + (v&1)*8] = z;
  }
  __syncthreads();
  bf8 qf[3];
  #pragma unroll
  for (int ks = 0; ks < 3; ++ks)
    qf[ks] = *(const bf8*)&Qs[(wave*16 + l16)*96 + ks*32 + quad*8];

  f32x4 o[5] = {};
  float mrun[4], lrun[4];
  #pragma unroll
  for (int r = 0; r < 4; ++r){ mrun[r] = -1e30f; lrun[r] = 0.f; }

  const int former = (g == 0) ? 0 : (g - 1);
  for (int c = 0; c < NCH; ++c){
    const int kbase = c*32;
    int krow0 = 0;
    if (MODE == 0){
      const int frame = (kbase >> 10) ? former : 0;
      krow0 = frame*SEQ + (kbase & (SEQ-1));
    }
    for (int v = tid; v < 320; v += 256){
      int r = v/10, c8 = (v - r*10)*8;
      long kr;
      if (MODE == 0) kr = krow0 + r;
      else { int j = kbase + r; j = j < NK ? j : NK-1; kr = (long)g*77 + j; }
      *(U4*)&Ks[r*96 + c8] = *(const U4*)&kbuf[kr*KLD + KCOL + h*HD + c8];
    }
    for (int v = tid; v < 320; v += 256){
      int d = v >> 2, k2 = (v & 3)*8;
      long vc = (MODE == 0) ? (long)(krow0 + k2) : (long)(g*80 + kbase + k2);
      *(U4*)&Vs[d*32 + k2] = *(const U4*)&vT[(long)(h*HD + d)*VLD + vc];
    }
    __syncthreads();
    if (MODE == 1 && kbase + 32 > NK){
      for (int v = tid; v < 80*32; v += 256)
        if (kbase + (v & 31) >= NK) Vs[v] = 0;
      __syncthreads();
    }
    f32x4 s0 = {}, s1 = {};
    #pragma unroll
    for (int ks = 0; ks < 3; ++ks){
      bf8 kf0 = *(const bf8*)&Ks[(l16)*96      + ks*32 + quad*8];
      bf8 kf1 = *(const bf8*)&Ks[(16 + l16)*96 + ks*32 + quad*8];
      s0 = __builtin_amdgcn_mfma_f32_16x16x32_bf16(qf[ks], kf0, s0, 0, 0, 0);
      s1 = __builtin_amdgcn_mfma_f32_16x16x32_bf16(qf[ks], kf1, s1, 0, 0, 0);
    }
    float alpha[4];
    #pragma unroll
    for (int r = 0; r < 4; ++r){
      float a0 = s0[r]*SCALE, a1 = s1[r]*SCALE;
      if (MODE == 1){
        if (kbase + l16 >= NK)      a0 = -1e30f;
        if (kbase + 16 + l16 >= NK) a1 = -1e30f;
      }
      float mx = fmaxf(a0, a1);
      mx = fmaxf(mx, __shfl_xor(mx, 1, 64));
      mx = fmaxf(mx, __shfl_xor(mx, 2, 64));
      mx = fmaxf(mx, __shfl_xor(mx, 4, 64));
      mx = fmaxf(mx, __shfl_xor(mx, 8, 64));
      float mn = fmaxf(mrun[r], mx);
      alpha[r] = __expf(mrun[r] - mn);
      float p0 = __expf(a0 - mn);
      float p1 = __expf(a1 - mn);
      float rs = p0 + p1;
      rs += __shfl_xor(rs, 1, 64); rs += __shfl_xor(rs, 2, 64);
      rs += __shfl_xor(rs, 4, 64); rs += __shfl_xor(rs, 8, 64);
      lrun[r] = lrun[r]*alpha[r] + rs;
      mrun[r] = mn;
      s0[r] = p0; s1[r] = p1;
    }
    #pragma unroll
    for (int dt = 0; dt < 5; ++dt)
      #pragma unroll
      for (int r = 0; r < 4; ++r) o[dt][r] *= alpha[r];
    #pragma unroll
    for (int r = 0; r < 4; ++r){
      Ps[wave][(quad*4 + r)*32 + l16]      = f2bf(s0[r]);
      Ps[wave][(quad*4 + r)*32 + 16 + l16] = f2bf(s1[r]);
    }
    asm volatile("s_waitcnt lgkmcnt(0)" ::: "memory");
    bf8 pf = *(const bf8*)&Ps[wave][l16*32 + quad*8];
    #pragma unroll
    for (int dt = 0; dt < 5; ++dt){
      bf8 vf = *(const bf8*)&Vs[(dt*16 + l16)*32 + quad*8];
      o[dt] = __builtin_amdgcn_mfma_f32_16x16x32_bf16(pf, vf, o[dt], 0, 0, 0);
    }
    __syncthreads();
  }
  const int orow0 = qrow0 + wave*16 + quad*4;
  #pragma unroll
  for (int dt = 0; dt < 5; ++dt){
    const int col = h*HD + dt*16 + l16;
    #pragma unroll
    for (int r = 0; r < 4; ++r)
      out[(long)(orow0 + r)*DIM + col] = f2bf(o[dt][r] / lrun[r]);
  }
}

// ---------------- host orchestration ---------------------------------------
extern "C" void kernel_launch(void* const* d_in, const int* in_sizes, int n_in,
                              void* d_out, int out_size, void* d_ws, size_t ws_size,
                              hipStream_t stream)
{
  const float* hidden = (const float*)d_in[0];
  const float* enc    = (const float*)d_in[1];
  const float* ln1w = (const float*)d_in[3],  *ln1b = (const float*)d_in[4];
  const float* q1   = (const float*)d_in[5],  *k1   = (const float*)d_in[6];
  const float* v1   = (const float*)d_in[7],  *o1w  = (const float*)d_in[8];
  const float* o1b  = (const float*)d_in[9];
  const float* ln2w = (const float*)d_in[10], *ln2b = (const float*)d_in[11];
  const float* q2   = (const float*)d_in[12], *k2   = (const float*)d_in[13];
  const float* v2   = (const float*)d_in[14], *o2w  = (const float*)d_in[15];
  const float* o2b  = (const float*)d_in[16];
  const float* ln3w = (const float*)d_in[17], *ln3b = (const float*)d_in[18];
  const float* fw1  = (const float*)d_in[19], *fb1  = (const float*)d_in[20];
  const float* fw2  = (const float*)d_in[21], *fb2  = (const float*)d_in[22];

  u16* ws = (u16*)d_ws;
  u16* Wqkv1T = ws;                           // 1920*640
  u16* o1T    = Wqkv1T + 1920*640;            // 640*640
  u16* q2T    = o1T    + 640*640;
  u16* Wkv2T  = q2T    + 640*640;             // 1280*768
  u16* o2T    = Wkv2T  + 1280*768;
  u16* W1T    = o2T    + 640*640;             // 5120*640
  u16* W2T    = W1T    + 5120*640;            // 640*2560
  u16* xbuf   = W2T    + 640*2560;            // 8192*640
  u16* qkv1   = xbuf   + (size_t)TOK*DIM;     // 8192*1920
  u16* v1T    = qkv1   + (size_t)TOK*3*DIM;   // 640*8192
  u16* ffin   = qkv1;                         // alias: 8192*2560 == qkv1+v1T
  u16* attnb  = v1T    + (size_t)DIM*TOK;     // 8192*640
  u16* hid2   = attnb  + (size_t)TOK*DIM;
  u16* hid3   = hid2   + (size_t)TOK*DIM;
  u16* q2buf  = hid3   + (size_t)TOK*DIM;
  u16* kv2    = q2buf  + (size_t)TOK*DIM;     // 616*1280
  u16* v2T    = kv2    + (size_t)ETOK*2*DIM;  // 640*640 + pad
  u16* encm   = v2T    + 640*640 + 64;        // 616*768
  u16* bln1w  = encm   + (size_t)ETOK*CROSS;
  u16* bln1b  = bln1w + DIM;
  u16* bo1b   = bln1b + DIM;
  u16* bln2w  = bo1b  + DIM;
  u16* bln2b  = bln2w + DIM;
  u16* bo2b   = bln2b + DIM;
  u16* bln3w  = bo2b  + DIM;
  u16* bln3b  = bln3w + DIM;
  u16* bfb2   = bln3b + DIM;
  u16* bfb1   = bfb2  + DIM;                  // 5120
  u16* wsend  = bfb1  + 2*FFI;
  const size_t needed = ((size_t)(wsend - ws) + 64) * 2;
  if (ws_size < needed) return;

  dim3 blk(256);
  // ---- stage 0: bf16 mirrors of fp32 inputs ----
  CvtJobs jobs;
  jobs.j[0]  = { enc,  encm,  ETOK*CROSS };
  jobs.j[1]  = { ln1w, bln1w, DIM };
  jobs.j[2]  = { ln1b, bln1b, DIM };
  jobs.j[3]  = { o1b,  bo1b,  DIM };
  jobs.j[4]  = { ln2w, bln2w, DIM };
  jobs.j[5]  = { ln2b, bln2b, DIM };
  jobs.j[6]  = { o2b,  bo2b,  DIM };
  jobs.j[7]  = { ln3w, bln3w, DIM };
  jobs.j[8]  = { ln3b, bln3b, DIM };
  jobs.j[9]  = { fb2,  bfb2,  DIM };
  jobs.j[10] = { fb1,  bfb1,  2*FFI };
  cvt_all<<<dim3(64,11), blk, 0, stream>>>(jobs);

  // ---- fused weight transposes into B^T layouts (tiled, all dims %64==0) --
  TJobs tj;
  tj.j[0] = { q1,  Wqkv1T,            640, 640,  640,  640 };
  tj.j[1] = { k1,  Wqkv1T + 640*640,  640, 640,  640,  640 };
  tj.j[2] = { v1,  Wqkv1T + 1280*640, 640, 640,  640,  640 };
  tj.j[3] = { o1w, o1T,               640, 640,  640,  640 };
  tj.j[4] = { q2,  q2T,               640, 640,  640,  640 };
  tj.j[5] = { k2,  Wkv2T,             768, 640,  640,  768 };
  tj.j[6] = { v2,  Wkv2T + 640*768,   768, 640,  640,  768 };
  tj.j[7] = { o2w, o2T,               640, 640,  640,  640 };
  tj.j[8] = { fw1, W1T,               640, 5120, 5120, 640 };
  tj.j[9] = { fw2, W2T,               2560,640,  640,  2560 };
  transpose_tiled<<<dim3(800,10), blk, 0, stream>>>(tj);

  // ---- block 1: LN1(fp32) -> qkv -> temporal attention -> o1 + res(fp32) ----
  ln_k<<<TOK, blk, 0, stream>>>(hidden, bln1w, bln1b, xbuf, 1);
  gemm_bt<128><<<dim3(15,64), blk, 0, stream>>>(xbuf, Wqkv1T, qkv1,
      TOK, 3*DIM, DIM, DIM, DIM, 3*DIM, nullptr, nullptr, 0, 0, 0);
  transpose_tile<<<dim3(10,128), blk, 0, stream>>>(qkv1 + 2*DIM, v1T, 3*DIM, TOK);
  attn_k<0><<<dim3(16,8,8), blk, 0, stream>>>(qkv1, qkv1, v1T, attnb);
  gemm_bt<64><<<dim3(10,64), blk, 0, stream>>>(attnb, o1T, hid2,
      TOK, DIM, DIM, DIM, DIM, DIM, bo1b, hidden, DIM, 1, 0);

  // ---- block 2: LN2 -> q2 / kv2 -> cross attention -> o2 + residual ----
  ln_k<<<TOK, blk, 0, stream>>>(hid2, bln2w, bln2b, xbuf, 0);
  gemm_bt<64><<<dim3(10,64), blk, 0, stream>>>(xbuf, q2T, q2buf,
      TOK, DIM, DIM, DIM, DIM, DIM, nullptr, nullptr, 0, 0, 0);
  gemm_bt<64><<<dim3(20,5), blk, 0, stream>>>(encm, Wkv2T, kv2,
      ETOK, 2*DIM, CROSS, CROSS, CROSS, 2*DIM, nullptr, nullptr, 0, 0, 0);
  transpose_v2<<<dim3((ETOK*DIM + 255)/256), blk, 0, stream>>>(kv2, v2T);
  attn_k<1><<<dim3(16,8,8), blk, 0, stream>>>(q2buf, kv2, v2T, attnb);
  gemm_bt<64><<<dim3(10,64), blk, 0, stream>>>(attnb, o2T, hid3,
      TOK, DIM, DIM, DIM, DIM, DIM, bo2b, hid2, DIM, 0, 0);

  // ---- block 3: LN3 -> GEGLU FF -> out(fp32) + residual ----
  ln_k<<<TOK, blk, 0, stream>>>(hid3, bln3w, bln3b, xbuf, 0);
  gemm_geglu<<<dim3(40,64), blk, 0, stream>>>(xbuf, W1T, ffin, bfb1);
  gemm_bt<64><<<dim3(10,64), blk, 0, stream>>>(ffin, W2T, d_out,
      TOK, DIM, FFI, FFI, FFI, DIM, bfb2, hid3, DIM, 0, 1);
}

// Round 2
// 790.301 us; speedup vs baseline: 1.5186x; 1.0243x over previous
//
#include <hip/hip_runtime.h>
#include <stdint.h>

#define TOK   8192        // 8 frames * 1024 tokens
#define DIM   640
#define HEADS 8
#define HD    80
#define SEQ   1024
#define CROSS 768
#define ETOK  616         // 8 * 77 encoder tokens
#define FFI   2560        // FF inner (half of 5120 proj)
#define SCALE 0.11180339887498949f

typedef unsigned short u16;
typedef unsigned int   u32;

using bf8   = __attribute__((ext_vector_type(8))) short;   // 8 bf16 (4 VGPRs)
using f32x4 = __attribute__((ext_vector_type(4))) float;   // MFMA C/D

struct __align__(16) U4 { u32 x, y, z, w; };
struct __align__(8)  U2 { u32 x, y; };

__device__ __forceinline__ float bf2f(u16 u){
  union { u32 i; float f; } v; v.i = ((u32)u) << 16; return v.f;
}
__device__ __forceinline__ u16 f2bf(float f){
  union { float f; u32 i; } v; v.f = f;
  u32 r = v.i + 0x7fffu + ((v.i >> 16) & 1u);
  return (u16)(r >> 16);
}
__device__ __forceinline__ u32 cvtpk_bf16(float lo, float hi){
  u32 r; asm("v_cvt_pk_bf16_f32 %0, %1, %2" : "=v"(r) : "v"(lo), "v"(hi)); return r;
}
__device__ __forceinline__ float gelu_t(float x){
  float y = 0.7978845608028654f * (x + 0.044715f * x * x * x);
  float e = __expf(2.f * y);
  return 0.5f * x * (2.f - 2.f / (e + 1.f));
}

// async global->LDS, 16B per lane; LDS dest is wave-uniform base + lane*16
__device__ __forceinline__ void gl2lds16(const u16* g, u16* l){
  __builtin_amdgcn_global_load_lds(
      (const __attribute__((address_space(1))) void*)g,
      (__attribute__((address_space(3))) void*)l, 16, 0, 0);
}

// ---------------- fp32 -> bf16 mirrors -------------------------------------
struct CvtJob  { const float* s; u16* d; int n; };
struct CvtJobs { CvtJob j[11]; };
__global__ __launch_bounds__(256) void cvt_all(CvtJobs jobs)
{
  const CvtJob jb = jobs.j[blockIdx.y];
  for (long i = (long)blockIdx.x*256 + threadIdx.x; i < jb.n; i += (long)gridDim.x*256)
    jb.d[i] = f2bf(jb.s[i]);
}

// ---------------- tiled weight transposes (fp32 src -> bf16 dst) -----------
struct TJob  { const float* s; u16* d; int R, C, srcLd, dstLd; };
struct TJobs { TJob j[10]; };
__global__ __launch_bounds__(256) void transpose_tiled(TJobs jobs)
{
  const TJob jb = jobs.j[blockIdx.y];
  const int tilesC = jb.C >> 6;
  const int nt = (jb.R >> 6) * tilesC;
  if ((int)blockIdx.x >= nt) return;
  const int tr = (blockIdx.x / tilesC) << 6, tc = (blockIdx.x % tilesC) << 6;
  __shared__ u16 t[64][65];
  const int tid = threadIdx.x;
  const int rr = tid >> 3, c8 = (tid & 7) * 8;
  #pragma unroll
  for (int p = 0; p < 2; ++p){
    const int r = rr + p*32;
    const float* s = &jb.s[(long)(tr + r)*jb.srcLd + tc + c8];
    #pragma unroll
    for (int j = 0; j < 8; ++j) t[r][c8 + j] = f2bf(s[j]);
  }
  __syncthreads();
  #pragma unroll
  for (int p = 0; p < 2; ++p){
    const int c = rr + p*32;
    u16 tmp[8];
    #pragma unroll
    for (int j = 0; j < 8; ++j) tmp[j] = t[c8 + j][c];
    *(U4*)&jb.d[(long)(tc + c)*jb.dstLd + tr + c8] = *(U4*)tmp;
  }
}

// ---------------- tiled bf16 transpose (v1T): R,C multiples of 64 ----------
__global__ __launch_bounds__(256) void transpose_tile(
    const u16* __restrict__ src, u16* __restrict__ dst,
    int srcLd, int dstLd)
{
  __shared__ u16 t[64][65];
  const int tr = blockIdx.y << 6, tc = blockIdx.x << 6;
  const int tid = threadIdx.x;
  const int rr = tid >> 3, c8 = (tid & 7) * 8;
  #pragma unroll
  for (int p = 0; p < 2; ++p){
    const int r = rr + p*32;
    U4 v = *(const U4*)&src[(long)(tr + r)*srcLd + tc + c8];
    const u16* pv = (const u16*)&v;
    #pragma unroll
    for (int j = 0; j < 8; ++j) t[r][c8 + j] = pv[j];
  }
  __syncthreads();
  #pragma unroll
  for (int p = 0; p < 2; ++p){
    const int c = rr + p*32;
    u16 tmp[8];
    #pragma unroll
    for (int j = 0; j < 8; ++j) tmp[j] = t[c8 + j][c];
    *(U4*)&dst[(long)(tc + c)*dstLd + tr + c8] = *(U4*)tmp;
  }
}

// v2 transpose with per-batch padding 77->80 (16B-aligned attention loads)
__global__ __launch_bounds__(256) void transpose_v2(
    const u16* __restrict__ src, u16* __restrict__ dst)
{
  int idx = blockIdx.x*256 + threadIdx.x;
  if (idx >= ETOK*DIM) return;
  int rr = idx / DIM, d = idx - rr*DIM;
  int g = rr / 77, j = rr - g*77;
  dst[(long)d*DIM + g*80 + j] = src[(long)rr*(2*DIM) + DIM + d];
}

// ---------------- LayerNorm: one block per row (src fp32 or bf16) ----------
__global__ __launch_bounds__(256) void ln_k(
    const void* __restrict__ src, const u16* __restrict__ w,
    const u16* __restrict__ b, u16* __restrict__ dst, int srcf32)
{
  __shared__ float xr[DIM];
  __shared__ float red[256];
  const int tid = threadIdx.x;
  const long row = blockIdx.x;
  float ls = 0.f;
  for (int i = tid; i < DIM; i += 256){
    float v = srcf32 ? ((const float*)src)[row*DIM + i]
                     : bf2f(((const u16*)src)[row*DIM + i]);
    xr[i] = v; ls += v;
  }
  red[tid] = ls; __syncthreads();
  for (int o = 128; o > 0; o >>= 1){ if (tid < o) red[tid] += red[tid+o]; __syncthreads(); }
  const float mean = red[0] * (1.f/DIM);
  __syncthreads();
  float lq = 0.f;
  for (int i = tid; i < DIM; i += 256){ float d = xr[i] - mean; lq += d*d; }
  red[tid] = lq; __syncthreads();
  for (int o = 128; o > 0; o >>= 1){ if (tid < o) red[tid] += red[tid+o]; __syncthreads(); }
  const float var = red[0] * (1.f/DIM);
  const float rs = rsqrtf(var + 1e-5f);
  u16* q = dst + row*DIM;
  for (int i = tid; i < DIM; i += 256)
    q[i] = f2bf((xr[i] - mean)*rs*bf2f(w[i]) + bf2f(b[i]));
}

// ---------------- MFMA GEMM, templated N-tile ------------------------------
template<int BN>
__global__ __launch_bounds__(256) void gemm_bt(
    const u16* __restrict__ A, const u16* __restrict__ BT, void* __restrict__ C,
    int M, int N, int K, int lda, int ldb, int ldc,
    const u16* __restrict__ bias, const void* __restrict__ res, int ldr,
    int resf32, int outf32)
{
  constexpr int NT  = BN/32;
  constexpr int BCH = BN/16;
  constexpr int BPW = BCH/4;
  __shared__ __align__(16) u16 sA[2][8*512];
  __shared__ __align__(16) u16 sB[2][BCH*512];
  const int tid  = threadIdx.x;
  const int wave = tid >> 6, lane = tid & 63;
  const int quad = lane >> 4, l16 = lane & 15;
  const int m0 = blockIdx.y * 128, n0 = blockIdx.x * BN;
  const int wm = (wave >> 1) * 64, wn = (wave & 1) * (BN/2);
  const int srow = lane & 15;
  const int scol = (lane >> 4) * 8;

  long aoff[2];
  #pragma unroll
  for (int i = 0; i < 2; ++i){
    int r = m0 + (wave*2 + i)*16 + srow;
    r = r < M ? r : M - 1;
    aoff[i] = (long)r*lda + scol;
  }
  long boff[BPW];
  #pragma unroll
  for (int i = 0; i < BPW; ++i){
    int r = n0 + (wave*BPW + i)*16 + srow;
    boff[i] = (long)r*ldb + scol;
  }

  f32x4 acc[4][NT] = {};
  #pragma unroll
  for (int i = 0; i < 2; ++i)   gl2lds16(&A[aoff[i]],  &sA[0][(wave*2 + i)*512]);
  #pragma unroll
  for (int i = 0; i < BPW; ++i) gl2lds16(&BT[boff[i]], &sB[0][(wave*BPW + i)*512]);
  __syncthreads();

  int cur = 0;
  for (int k0 = 0; ; ){
    const int kn = k0 + 32;
    if (kn < K){
      #pragma unroll
      for (int i = 0; i < 2; ++i)   gl2lds16(&A[aoff[i] + kn],  &sA[cur^1][(wave*2 + i)*512]);
      #pragma unroll
      for (int i = 0; i < BPW; ++i) gl2lds16(&BT[boff[i] + kn], &sB[cur^1][(wave*BPW + i)*512]);
    }
    bf8 a[4], b[NT];
    #pragma unroll
    for (int mt = 0; mt < 4; ++mt)  a[mt] = *(const bf8*)&sA[cur][((wm>>4) + mt)*512 + lane*8];
    #pragma unroll
    for (int nt = 0; nt < NT; ++nt) b[nt] = *(const bf8*)&sB[cur][((wn>>4) + nt)*512 + lane*8];
    #pragma unroll
    for (int mt = 0; mt < 4; ++mt)
      #pragma unroll
      for (int nt = 0; nt < NT; ++nt)
        acc[mt][nt] = __builtin_amdgcn_mfma_f32_16x16x32_bf16(a[mt], b[nt], acc[mt][nt], 0, 0, 0);
    k0 = kn;
    if (k0 >= K) break;
    __syncthreads();
    cur ^= 1;
  }
  #pragma unroll
  for (int mt = 0; mt < 4; ++mt){
    const int rl = wm + mt*16 + quad*4;
    #pragma unroll
    for (int nt = 0; nt < NT; ++nt){
      const int col = n0 + wn + nt*16 + l16;
      float bv = bias ? bf2f(bias[col]) : 0.f;
      #pragma unroll
      for (int r = 0; r < 4; ++r){
        int row = m0 + rl + r;
        if (row < M){
          float v = acc[mt][nt][r] + bv;
          if (res) v += resf32 ? ((const float*)res)[(long)row*ldr + col]
                               : bf2f(((const u16*)res)[(long)row*ldr + col]);
          if (outf32) ((float*)C)[(long)row*ldc + col] = v;
          else        ((u16*)C) [(long)row*ldc + col] = f2bf(v);
        }
      }
    }
  }
}

// ---------------- fused GEGLU GEMM, 128x64 tile ----------------------------
__global__ __launch_bounds__(256) void gemm_geglu(
    const u16* __restrict__ A, const u16* __restrict__ W, u16* __restrict__ C,
    const u16* __restrict__ bias)
{
  __shared__ __align__(16) u16 sA[2][8*512];
  __shared__ __align__(16) u16 sH[2][4*512];
  __shared__ __align__(16) u16 sG[2][4*512];
  const int tid  = threadIdx.x;
  const int wave = tid >> 6, lane = tid & 63;
  const int quad = lane >> 4, l16 = lane & 15;
  const int m0 = blockIdx.y * 128, n0 = blockIdx.x * 64;
  const int wm = (wave >> 1) * 64, wn = (wave & 1) * 32;
  const int srow = lane & 15;
  const int scol = (lane >> 4) * 8;

  long aoff[2];
  #pragma unroll
  for (int i = 0; i < 2; ++i)
    aoff[i] = (long)(m0 + (wave*2 + i)*16 + srow)*DIM + scol;
  const long hoff = (long)(n0 + wave*16 + srow)*DIM + scol;
  const long goff = (long)(FFI + n0 + wave*16 + srow)*DIM + scol;

  f32x4 ah[4][2] = {}, ag[4][2] = {};
  #pragma unroll
  for (int i = 0; i < 2; ++i) gl2lds16(&A[aoff[i]], &sA[0][(wave*2 + i)*512]);
  gl2lds16(&W[hoff], &sH[0][wave*512]);
  gl2lds16(&W[goff], &sG[0][wave*512]);
  __syncthreads();

  int cur = 0;
  for (int k0 = 0; ; ){
    const int kn = k0 + 32;
    if (kn < DIM){
      #pragma unroll
      for (int i = 0; i < 2; ++i) gl2lds16(&A[aoff[i] + kn], &sA[cur^1][(wave*2 + i)*512]);
      gl2lds16(&W[hoff + kn], &sH[cur^1][wave*512]);
      gl2lds16(&W[goff + kn], &sG[cur^1][wave*512]);
    }
    bf8 a[4];
    #pragma unroll
    for (int mt = 0; mt < 4; ++mt) a[mt] = *(const bf8*)&sA[cur][((wm>>4) + mt)*512 + lane*8];
    #pragma unroll
    for (int nt = 0; nt < 2; ++nt){
      bf8 bh = *(const bf8*)&sH[cur][((wn>>4) + nt)*512 + lane*8];
      bf8 bg = *(const bf8*)&sG[cur][((wn>>4) + nt)*512 + lane*8];
      #pragma unroll
      for (int mt = 0; mt < 4; ++mt){
        ah[mt][nt] = __builtin_amdgcn_mfma_f32_16x16x32_bf16(a[mt], bh, ah[mt][nt], 0, 0, 0);
        ag[mt][nt] = __builtin_amdgcn_mfma_f32_16x16x32_bf16(a[mt], bg, ag[mt][nt], 0, 0, 0);
      }
    }
    k0 = kn;
    if (k0 >= DIM) break;
    __syncthreads();
    cur ^= 1;
  }
  #pragma unroll
  for (int mt = 0; mt < 4; ++mt){
    const int rl = wm + mt*16 + quad*4;
    #pragma unroll
    for (int nt = 0; nt < 2; ++nt){
      const int col = n0 + wn + nt*16 + l16;
      const float bh = bf2f(bias[col]);
      const float bg = bf2f(bias[FFI + col]);
      #pragma unroll
      for (int r = 0; r < 4; ++r){
        int row = m0 + rl + r;
        float h = ah[mt][nt][r] + bh;
        float g = ag[mt][nt][r] + bg;
        C[(long)row*FFI + col] = f2bf(h * gelu_t(g));
      }
    }
  }
}

// ---------------- MFMA flash attention, swapped-QK^T (lane-local softmax) ---
// S^T = mfma(K, Q): lane holds 8 scores for q = l16, k = quad*4+r (+16).
// Row reduce: in-lane + 2 cross-quad shfls. Defer-max (T13), exp2 softmax,
// cvt_pk P->bf16, reg-prefetched K/V staging (T14), padded LDS strides.
template<int MODE>
__global__ __launch_bounds__(256) void attn_k(
    const u16* __restrict__ qbuf, const u16* __restrict__ kbuf,
    const u16* __restrict__ vT, u16* __restrict__ out)
{
  constexpr int QLD  = MODE ? DIM      : 3*DIM;
  constexpr int KLD  = MODE ? 2*DIM    : 3*DIM;
  constexpr int KCOL = MODE ? 0        : DIM;
  constexpr int VLD  = MODE ? DIM      : TOK;
  constexpr int NK   = MODE ? 77       : 2*SEQ;
  constexpr int NCH  = MODE ? 3        : 64;
  constexpr float C1   = SCALE * 1.4426950408889634f;   // scale * log2(e)
  constexpr float THRR = 8.0f / C1;                     // defer-max threshold (raw)

  const int qt = blockIdx.x, h = blockIdx.y, g = blockIdx.z;
  const int tid = threadIdx.x, wave = tid >> 6, lane = tid & 63;
  const int quad = lane >> 4, l16 = lane & 15;

  __shared__ __align__(16) u16 Qs[64*104];
  __shared__ __align__(16) u16 Ks[32*104];
  __shared__ __align__(16) u16 Vs[80*40];
  __shared__ __align__(16) u16 Ps[4][16*40];

  const int qrow0 = g*SEQ + qt*64;
  // ---- stage Q (once) + zero pads ----
  for (int v = tid; v < 640; v += 256){
    int r = v/10, c8 = (v - r*10)*8;
    *(U4*)&Qs[r*104 + c8] = *(const U4*)&qbuf[(long)(qrow0 + r)*QLD + h*HD + c8];
  }
  for (int v = tid; v < 128; v += 256){
    U4 z = {0,0,0,0};
    *(U4*)&Qs[(v>>1)*104 + 80 + (v&1)*8] = z;
  }
  for (int v = tid; v < 64; v += 256){
    U4 z = {0,0,0,0};
    *(U4*)&Ks[(v>>1)*104 + 80 + (v&1)*8] = z;
  }

  // per-thread staging coordinates (loop-invariant)
  const int kr0 = tid/10,        kc0 = (tid - kr0*10)*8;
  const int kr1 = (tid+256)/10,  kc1 = ((tid+256) - kr1*10)*8;
  const int vd0 = tid >> 2,      vk0 = (tid & 3)*8;
  const int vd1 = (tid+256) >> 2;
  const int former = (g == 0) ? 0 : (g - 1);

  auto krow_of = [&](int c)->int{
    if (MODE == 0){
      int kb = c*32;
      int fr = (kb >> 10) ? former : 0;
      return fr*SEQ + (kb & (SEQ-1));
    }
    return 0;
  };
  U4 kA, kB, vA, vB;
  auto load_regs = [&](int c){
    if (MODE == 0){
      int kro = krow_of(c);
      kA = *(const U4*)&kbuf[(long)(kro + kr0)*KLD + KCOL + h*HD + kc0];
      if (tid < 64) kB = *(const U4*)&kbuf[(long)(kro + kr1)*KLD + KCOL + h*HD + kc1];
      vA = *(const U4*)&vT[(long)(h*HD + vd0)*VLD + kro + vk0];
      if (tid < 64) vB = *(const U4*)&vT[(long)(h*HD + vd1)*VLD + kro + vk0];
    } else {
      int kb = c*32;
      int j0 = kb + kr0; j0 = j0 < NK ? j0 : NK-1;
      kA = *(const U4*)&kbuf[((long)g*77 + j0)*KLD + KCOL + h*HD + kc0];
      if (tid < 64){
        int j1 = kb + kr1; j1 = j1 < NK ? j1 : NK-1;
        kB = *(const U4*)&kbuf[((long)g*77 + j1)*KLD + KCOL + h*HD + kc1];
      }
      vA = *(const U4*)&vT[(long)(h*HD + vd0)*VLD + g*80 + kb + vk0];
      if (tid < 64) vB = *(const U4*)&vT[(long)(h*HD + vd1)*VLD + g*80 + kb + vk0];
    }
  };
  load_regs(0);
  __syncthreads();      // Q visible

  bf8 qf[3];
  #pragma unroll
  for (int ks = 0; ks < 3; ++ks)
    qf[ks] = *(const bf8*)&Qs[(wave*16 + l16)*104 + ks*32 + quad*8];

  f32x4 o[5] = {};
  float mrun = -1e30f, lrun = 0.f, nmc = 0.f;

  for (int c = 0; c < NCH; ++c){
    const int kbase = c*32;
    // write staged regs (compiler waits vmcnt before ds_write)
    *(U4*)&Ks[kr0*104 + kc0] = kA;
    if (tid < 64) *(U4*)&Ks[kr1*104 + kc1] = kB;
    *(U4*)&Vs[vd0*40 + vk0] = vA;
    if (tid < 64) *(U4*)&Vs[vd1*40 + vk0] = vB;
    __syncthreads();
    if (MODE == 1 && kbase + 32 > NK){
      for (int v = tid; v < 80*32; v += 256){
        int d = v >> 5, cc = v & 31;
        if (kbase + cc >= NK) Vs[d*40 + cc] = 0;
      }
      __syncthreads();
    }
    if (c + 1 < NCH) load_regs(c + 1);   // async prefetch under compute

    f32x4 s0 = {}, s1 = {};
    __builtin_amdgcn_s_setprio(1);
    #pragma unroll
    for (int ks = 0; ks < 3; ++ks){
      bf8 kf0 = *(const bf8*)&Ks[l16*104        + ks*32 + quad*8];
      bf8 kf1 = *(const bf8*)&Ks[(16 + l16)*104 + ks*32 + quad*8];
      s0 = __builtin_amdgcn_mfma_f32_16x16x32_bf16(kf0, qf[ks], s0, 0, 0, 0);
      s1 = __builtin_amdgcn_mfma_f32_16x16x32_bf16(kf1, qf[ks], s1, 0, 0, 0);
    }
    __builtin_amdgcn_s_setprio(0);

    if (MODE == 1){
      const int kg = kbase + quad*4;
      #pragma unroll
      for (int r = 0; r < 4; ++r){
        if (kg + r >= NK)      s0[r] = -1e30f;
        if (kg + 16 + r >= NK) s1[r] = -1e30f;
      }
    }
    float mxs = fmaxf(fmaxf(fmaxf(s0[0],s0[1]), fmaxf(s0[2],s0[3])),
                      fmaxf(fmaxf(s1[0],s1[1]), fmaxf(s1[2],s1[3])));
    mxs = fmaxf(mxs, __shfl_xor(mxs, 16, 64));
    mxs = fmaxf(mxs, __shfl_xor(mxs, 32, 64));
    if (!__all(mxs - mrun <= THRR)){
      float mn = fmaxf(mrun, mxs);
      float al = exp2f((mrun - mn)*C1);
      mrun = mn; nmc = -mrun*C1;
      lrun *= al;
      float a0 = __shfl(al, quad*4 + 0, 16);
      float a1 = __shfl(al, quad*4 + 1, 16);
      float a2 = __shfl(al, quad*4 + 2, 16);
      float a3 = __shfl(al, quad*4 + 3, 16);
      #pragma unroll
      for (int dt = 0; dt < 5; ++dt){
        o[dt][0] *= a0; o[dt][1] *= a1; o[dt][2] *= a2; o[dt][3] *= a3;
      }
    }
    #pragma unroll
    for (int r = 0; r < 4; ++r){
      s0[r] = exp2f(__builtin_fmaf(s0[r], C1, nmc));
      s1[r] = exp2f(__builtin_fmaf(s1[r], C1, nmc));
    }
    float rs = ((s0[0]+s0[1])+(s0[2]+s0[3])) + ((s1[0]+s1[1])+(s1[2]+s1[3]));
    rs += __shfl_xor(rs, 16, 64);
    rs += __shfl_xor(rs, 32, 64);
    lrun += rs;

    U2 w01, w23;
    w01.x = cvtpk_bf16(s0[0], s0[1]);  w01.y = cvtpk_bf16(s0[2], s0[3]);
    w23.x = cvtpk_bf16(s1[0], s1[1]);  w23.y = cvtpk_bf16(s1[2], s1[3]);
    U2* pr = (U2*)&Ps[wave][l16*40];
    pr[quad]     = w01;    // k cols quad*4 .. quad*4+3
    pr[4 + quad] = w23;    // k cols 16+quad*4 ..
    asm volatile("s_waitcnt lgkmcnt(0)" ::: "memory");
    bf8 pf = *(const bf8*)&Ps[wave][l16*40 + quad*8];
    __builtin_amdgcn_s_setprio(1);
    #pragma unroll
    for (int dt = 0; dt < 5; ++dt){
      bf8 vf = *(const bf8*)&Vs[(dt*16 + l16)*40 + quad*8];
      o[dt] = __builtin_amdgcn_mfma_f32_16x16x32_bf16(pf, vf, o[dt], 0, 0, 0);
    }
    __builtin_amdgcn_s_setprio(0);
    __syncthreads();
  }

  float linv[4];
  #pragma unroll
  for (int r = 0; r < 4; ++r)
    linv[r] = __builtin_amdgcn_rcpf(__shfl(lrun, quad*4 + r, 16));
  const int orow0 = qrow0 + wave*16 + quad*4;
  #pragma unroll
  for (int dt = 0; dt < 5; ++dt){
    const int col = h*HD + dt*16 + l16;
    #pragma unroll
    for (int r = 0; r < 4; ++r)
      out[(long)(orow0 + r)*DIM + col] = f2bf(o[dt][r] * linv[r]);
  }
}

// ---------------- host orchestration ---------------------------------------
extern "C" void kernel_launch(void* const* d_in, const int* in_sizes, int n_in,
                              void* d_out, int out_size, void* d_ws, size_t ws_size,
                              hipStream_t stream)
{
  const float* hidden = (const float*)d_in[0];
  const float* enc    = (const float*)d_in[1];
  const float* ln1w = (const float*)d_in[3],  *ln1b = (const float*)d_in[4];
  const float* q1   = (const float*)d_in[5],  *k1   = (const float*)d_in[6];
  const float* v1   = (const float*)d_in[7],  *o1w  = (const float*)d_in[8];
  const float* o1b  = (const float*)d_in[9];
  const float* ln2w = (const float*)d_in[10], *ln2b = (const float*)d_in[11];
  const float* q2   = (const float*)d_in[12], *k2   = (const float*)d_in[13];
  const float* v2   = (const float*)d_in[14], *o2w  = (const float*)d_in[15];
  const float* o2b  = (const float*)d_in[16];
  const float* ln3w = (const float*)d_in[17], *ln3b = (const float*)d_in[18];
  const float* fw1  = (const float*)d_in[19], *fb1  = (const float*)d_in[20];
  const float* fw2  = (const float*)d_in[21], *fb2  = (const float*)d_in[22];

  u16* ws = (u16*)d_ws;
  u16* Wqkv1T = ws;                           // 1920*640
  u16* o1T    = Wqkv1T + 1920*640;            // 640*640
  u16* q2T    = o1T    + 640*640;
  u16* Wkv2T  = q2T    + 640*640;             // 1280*768
  u16* o2T    = Wkv2T  + 1280*768;
  u16* W1T    = o2T    + 640*640;             // 5120*640
  u16* W2T    = W1T    + 5120*640;            // 640*2560
  u16* xbuf   = W2T    + 640*2560;            // 8192*640
  u16* qkv1   = xbuf   + (size_t)TOK*DIM;     // 8192*1920
  u16* v1T    = qkv1   + (size_t)TOK*3*DIM;   // 640*8192
  u16* ffin   = qkv1;                         // alias: 8192*2560 == qkv1+v1T
  u16* attnb  = v1T    + (size_t)DIM*TOK;     // 8192*640
  u16* hid2   = attnb  + (size_t)TOK*DIM;
  u16* hid3   = hid2   + (size_t)TOK*DIM;
  u16* q2buf  = hid3   + (size_t)TOK*DIM;
  u16* kv2    = q2buf  + (size_t)TOK*DIM;     // 616*1280
  u16* v2T    = kv2    + (size_t)ETOK*2*DIM;  // 640*640 + pad
  u16* encm   = v2T    + 640*640 + 64;        // 616*768
  u16* bln1w  = encm   + (size_t)ETOK*CROSS;
  u16* bln1b  = bln1w + DIM;
  u16* bo1b   = bln1b + DIM;
  u16* bln2w  = bo1b  + DIM;
  u16* bln2b  = bln2w + DIM;
  u16* bo2b   = bln2b + DIM;
  u16* bln3w  = bo2b  + DIM;
  u16* bln3b  = bln3w + DIM;
  u16* bfb2   = bln3b + DIM;
  u16* bfb1   = bfb2  + DIM;                  // 5120
  u16* wsend  = bfb1  + 2*FFI;
  const size_t needed = ((size_t)(wsend - ws) + 64) * 2;
  if (ws_size < needed) return;

  dim3 blk(256);
  // ---- stage 0: bf16 mirrors of fp32 inputs ----
  CvtJobs jobs;
  jobs.j[0]  = { enc,  encm,  ETOK*CROSS };
  jobs.j[1]  = { ln1w, bln1w, DIM };
  jobs.j[2]  = { ln1b, bln1b, DIM };
  jobs.j[3]  = { o1b,  bo1b,  DIM };
  jobs.j[4]  = { ln2w, bln2w, DIM };
  jobs.j[5]  = { ln2b, bln2b, DIM };
  jobs.j[6]  = { o2b,  bo2b,  DIM };
  jobs.j[7]  = { ln3w, bln3w, DIM };
  jobs.j[8]  = { ln3b, bln3b, DIM };
  jobs.j[9]  = { fb2,  bfb2,  DIM };
  jobs.j[10] = { fb1,  bfb1,  2*FFI };
  cvt_all<<<dim3(64,11), blk, 0, stream>>>(jobs);

  // ---- fused weight transposes into B^T layouts (tiled, all dims %64==0) --
  TJobs tj;
  tj.j[0] = { q1,  Wqkv1T,            640, 640,  640,  640 };
  tj.j[1] = { k1,  Wqkv1T + 640*640,  640, 640,  640,  640 };
  tj.j[2] = { v1,  Wqkv1T + 1280*640, 640, 640,  640,  640 };
  tj.j[3] = { o1w, o1T,               640, 640,  640,  640 };
  tj.j[4] = { q2,  q2T,               640, 640,  640,  640 };
  tj.j[5] = { k2,  Wkv2T,             768, 640,  640,  768 };
  tj.j[6] = { v2,  Wkv2T + 640*768,   768, 640,  640,  768 };
  tj.j[7] = { o2w, o2T,               640, 640,  640,  640 };
  tj.j[8] = { fw1, W1T,               640, 5120, 5120, 640 };
  tj.j[9] = { fw2, W2T,               2560,640,  640,  2560 };
  transpose_tiled<<<dim3(800,10), blk, 0, stream>>>(tj);

  // ---- block 1: LN1(fp32) -> qkv -> temporal attention -> o1 + res(fp32) ----
  ln_k<<<TOK, blk, 0, stream>>>(hidden, bln1w, bln1b, xbuf, 1);
  gemm_bt<128><<<dim3(15,64), blk, 0, stream>>>(xbuf, Wqkv1T, qkv1,
      TOK, 3*DIM, DIM, DIM, DIM, 3*DIM, nullptr, nullptr, 0, 0, 0);
  transpose_tile<<<dim3(10,128), blk, 0, stream>>>(qkv1 + 2*DIM, v1T, 3*DIM, TOK);
  attn_k<0><<<dim3(16,8,8), blk, 0, stream>>>(qkv1, qkv1, v1T, attnb);
  gemm_bt<64><<<dim3(10,64), blk, 0, stream>>>(attnb, o1T, hid2,
      TOK, DIM, DIM, DIM, DIM, DIM, bo1b, hidden, DIM, 1, 0);

  // ---- block 2: LN2 -> q2 / kv2 -> cross attention -> o2 + residual ----
  ln_k<<<TOK, blk, 0, stream>>>(hid2, bln2w, bln2b, xbuf, 0);
  gemm_bt<64><<<dim3(10,64), blk, 0, stream>>>(xbuf, q2T, q2buf,
      TOK, DIM, DIM, DIM, DIM, DIM, nullptr, nullptr, 0, 0, 0);
  gemm_bt<64><<<dim3(20,5), blk, 0, stream>>>(encm, Wkv2T, kv2,
      ETOK, 2*DIM, CROSS, CROSS, CROSS, 2*DIM, nullptr, nullptr, 0, 0, 0);
  transpose_v2<<<dim3((ETOK*DIM + 255)/256), blk, 0, stream>>>(kv2, v2T);
  attn_k<1><<<dim3(16,8,8), blk, 0, stream>>>(q2buf, kv2, v2T, attnb);
  gemm_bt<64><<<dim3(10,64), blk, 0, stream>>>(attnb, o2T, hid3,
      TOK, DIM, DIM, DIM, DIM, DIM, bo2b, hid2, DIM, 0, 0);

  // ---- block 3: LN3 -> GEGLU FF -> out(fp32) + residual ----
  ln_k<<<TOK, blk, 0, stream>>>(hid3, bln3w, bln3b, xbuf, 0);
  gemm_geglu<<<dim3(40,64), blk, 0, stream>>>(xbuf, W1T, ffin, bfb1);
  gemm_bt<64><<<dim3(10,64), blk, 0, stream>>>(ffin, W2T, d_out,
      TOK, DIM, FFI, FFI, FFI, DIM, bfb2, hid3, DIM, 0, 1);
}

// Round 4
// 726.333 us; speedup vs baseline: 1.6524x; 1.0881x over previous
//
#include <hip/hip_runtime.h>
#include <stdint.h>

#define TOK   8192        // 8 frames * 1024 tokens
#define DIM   640
#define HEADS 8
#define HD    80
#define SEQ   1024
#define CROSS 768
#define ETOK  616         // 8 * 77 encoder tokens
#define FFI   2560        // FF inner (half of 5120 proj)
#define SCALE 0.11180339887498949f

typedef unsigned short u16;
typedef unsigned int   u32;

using bf8   = __attribute__((ext_vector_type(8))) short;   // 8 bf16 (4 VGPRs)
using f32x4 = __attribute__((ext_vector_type(4))) float;   // MFMA C/D

struct __align__(16) U4 { u32 x, y, z, w; };
struct __align__(8)  U2 { u32 x, y; };

__device__ __forceinline__ float bf2f(u16 u){
  union { u32 i; float f; } v; v.i = ((u32)u) << 16; return v.f;
}
__device__ __forceinline__ u16 f2bf(float f){
  union { float f; u32 i; } v; v.f = f;
  u32 r = v.i + 0x7fffu + ((v.i >> 16) & 1u);
  return (u16)(r >> 16);
}
__device__ __forceinline__ u32 cvtpk_bf16(float lo, float hi){
  u32 r; asm("v_cvt_pk_bf16_f32 %0, %1, %2" : "=v"(r) : "v"(lo), "v"(hi)); return r;
}
__device__ __forceinline__ float gelu_t(float x){
  float y = 0.7978845608028654f * (x + 0.044715f * x * x * x);
  float e = __expf(2.f * y);
  return 0.5f * x * (2.f - 2.f / (e + 1.f));
}

// async global->LDS, 16B per lane; LDS dest is wave-uniform base + lane*16
__device__ __forceinline__ void gl2lds16(const u16* g, u16* l){
  __builtin_amdgcn_global_load_lds(
      (const __attribute__((address_space(1))) void*)g,
      (__attribute__((address_space(3))) void*)l, 16, 0, 0);
}

// ---------------- tiny zero block (OOB redirect target) --------------------
__global__ void zero_k(u16* p){ p[threadIdx.x] = 0; }

// ---------------- fp32 -> bf16 mirrors -------------------------------------
struct CvtJob  { const float* s; u16* d; int n; };
struct CvtJobs { CvtJob j[11]; };
__global__ __launch_bounds__(256) void cvt_all(CvtJobs jobs)
{
  const CvtJob jb = jobs.j[blockIdx.y];
  for (long i = (long)blockIdx.x*256 + threadIdx.x; i < jb.n; i += (long)gridDim.x*256)
    jb.d[i] = f2bf(jb.s[i]);
}

// ---------------- tiled weight transposes (fp32 src -> bf16 dst) -----------
struct TJob  { const float* s; u16* d; int R, C, srcLd, dstLd; };
struct TJobs { TJob j[10]; };
__global__ __launch_bounds__(256) void transpose_tiled(TJobs jobs)
{
  const TJob jb = jobs.j[blockIdx.y];
  const int tilesC = jb.C >> 6;
  const int nt = (jb.R >> 6) * tilesC;
  if ((int)blockIdx.x >= nt) return;
  const int tr = (blockIdx.x / tilesC) << 6, tc = (blockIdx.x % tilesC) << 6;
  __shared__ u16 t[64][65];
  const int tid = threadIdx.x;
  const int rr = tid >> 3, c8 = (tid & 7) * 8;
  #pragma unroll
  for (int p = 0; p < 2; ++p){
    const int r = rr + p*32;
    const float* s = &jb.s[(long)(tr + r)*jb.srcLd + tc + c8];
    #pragma unroll
    for (int j = 0; j < 8; ++j) t[r][c8 + j] = f2bf(s[j]);
  }
  __syncthreads();
  #pragma unroll
  for (int p = 0; p < 2; ++p){
    const int c = rr + p*32;
    u16 tmp[8];
    #pragma unroll
    for (int j = 0; j < 8; ++j) tmp[j] = t[c8 + j][c];
    *(U4*)&jb.d[(long)(tc + c)*jb.dstLd + tr + c8] = *(U4*)tmp;
  }
}

// ---------------- tiled bf16 transpose (v1T): R,C multiples of 64 ----------
__global__ __launch_bounds__(256) void transpose_tile(
    const u16* __restrict__ src, u16* __restrict__ dst,
    int srcLd, int dstLd)
{
  __shared__ u16 t[64][65];
  const int tr = blockIdx.y << 6, tc = blockIdx.x << 6;
  const int tid = threadIdx.x;
  const int rr = tid >> 3, c8 = (tid & 7) * 8;
  #pragma unroll
  for (int p = 0; p < 2; ++p){
    const int r = rr + p*32;
    U4 v = *(const U4*)&src[(long)(tr + r)*srcLd + tc + c8];
    const u16* pv = (const u16*)&v;
    #pragma unroll
    for (int j = 0; j < 8; ++j) t[r][c8 + j] = pv[j];
  }
  __syncthreads();
  #pragma unroll
  for (int p = 0; p < 2; ++p){
    const int c = rr + p*32;
    u16 tmp[8];
    #pragma unroll
    for (int j = 0; j < 8; ++j) tmp[j] = t[c8 + j][c];
    *(U4*)&dst[(long)(tc + c)*dstLd + tr + c8] = *(U4*)tmp;
  }
}

// v2 transpose with per-batch padding 77->80; pad columns ZEROED so the
// attention V tail (keys 77..79) contributes exactly 0
__global__ __launch_bounds__(256) void transpose_v2(
    const u16* __restrict__ src, u16* __restrict__ dst)
{
  int idx = blockIdx.x*256 + threadIdx.x;
  if (idx >= DIM*640) return;
  int d = idx / 640, c = idx - d*640;
  int g = c / 80, j = c - g*80;
  u16 v = 0;
  if (j < 77) v = src[(long)(g*77 + j)*(2*DIM) + DIM + d];
  dst[(long)d*640 + c] = v;
}

// ---------------- LayerNorm: one block per row (src fp32 or bf16) ----------
__global__ __launch_bounds__(256) void ln_k(
    const void* __restrict__ src, const u16* __restrict__ w,
    const u16* __restrict__ b, u16* __restrict__ dst, int srcf32)
{
  __shared__ float xr[DIM];
  __shared__ float red[256];
  const int tid = threadIdx.x;
  const long row = blockIdx.x;
  float ls = 0.f;
  for (int i = tid; i < DIM; i += 256){
    float v = srcf32 ? ((const float*)src)[row*DIM + i]
                     : bf2f(((const u16*)src)[row*DIM + i]);
    xr[i] = v; ls += v;
  }
  red[tid] = ls; __syncthreads();
  for (int o = 128; o > 0; o >>= 1){ if (tid < o) red[tid] += red[tid+o]; __syncthreads(); }
  const float mean = red[0] * (1.f/DIM);
  __syncthreads();
  float lq = 0.f;
  for (int i = tid; i < DIM; i += 256){ float d = xr[i] - mean; lq += d*d; }
  red[tid] = lq; __syncthreads();
  for (int o = 128; o > 0; o >>= 1){ if (tid < o) red[tid] += red[tid+o]; __syncthreads(); }
  const float var = red[0] * (1.f/DIM);
  const float rs = rsqrtf(var + 1e-5f);
  u16* q = dst + row*DIM;
  for (int i = tid; i < DIM; i += 256)
    q[i] = f2bf((xr[i] - mean)*rs*bf2f(w[i]) + bf2f(b[i]));
}

// ---------------- MFMA GEMM, templated N-tile ------------------------------
template<int BN>
__global__ __launch_bounds__(256) void gemm_bt(
    const u16* __restrict__ A, const u16* __restrict__ BT, void* __restrict__ C,
    int M, int N, int K, int lda, int ldb, int ldc,
    const u16* __restrict__ bias, const void* __restrict__ res, int ldr,
    int resf32, int outf32)
{
  constexpr int NT  = BN/32;
  constexpr int BCH = BN/16;
  constexpr int BPW = BCH/4;
  __shared__ __align__(16) u16 sA[2][8*512];
  __shared__ __align__(16) u16 sB[2][BCH*512];
  const int tid  = threadIdx.x;
  const int wave = tid >> 6, lane = tid & 63;
  const int quad = lane >> 4, l16 = lane & 15;
  const int m0 = blockIdx.y * 128, n0 = blockIdx.x * BN;
  const int wm = (wave >> 1) * 64, wn = (wave & 1) * (BN/2);
  const int srow = lane & 15;
  const int scol = (lane >> 4) * 8;

  long aoff[2];
  #pragma unroll
  for (int i = 0; i < 2; ++i){
    int r = m0 + (wave*2 + i)*16 + srow;
    r = r < M ? r : M - 1;
    aoff[i] = (long)r*lda + scol;
  }
  long boff[BPW];
  #pragma unroll
  for (int i = 0; i < BPW; ++i){
    int r = n0 + (wave*BPW + i)*16 + srow;
    boff[i] = (long)r*ldb + scol;
  }

  f32x4 acc[4][NT] = {};
  #pragma unroll
  for (int i = 0; i < 2; ++i)   gl2lds16(&A[aoff[i]],  &sA[0][(wave*2 + i)*512]);
  #pragma unroll
  for (int i = 0; i < BPW; ++i) gl2lds16(&BT[boff[i]], &sB[0][(wave*BPW + i)*512]);
  __syncthreads();

  int cur = 0;
  for (int k0 = 0; ; ){
    const int kn = k0 + 32;
    if (kn < K){
      #pragma unroll
      for (int i = 0; i < 2; ++i)   gl2lds16(&A[aoff[i] + kn],  &sA[cur^1][(wave*2 + i)*512]);
      #pragma unroll
      for (int i = 0; i < BPW; ++i) gl2lds16(&BT[boff[i] + kn], &sB[cur^1][(wave*BPW + i)*512]);
    }
    bf8 a[4], b[NT];
    #pragma unroll
    for (int mt = 0; mt < 4; ++mt)  a[mt] = *(const bf8*)&sA[cur][((wm>>4) + mt)*512 + lane*8];
    #pragma unroll
    for (int nt = 0; nt < NT; ++nt) b[nt] = *(const bf8*)&sB[cur][((wn>>4) + nt)*512 + lane*8];
    #pragma unroll
    for (int mt = 0; mt < 4; ++mt)
      #pragma unroll
      for (int nt = 0; nt < NT; ++nt)
        acc[mt][nt] = __builtin_amdgcn_mfma_f32_16x16x32_bf16(a[mt], b[nt], acc[mt][nt], 0, 0, 0);
    k0 = kn;
    if (k0 >= K) break;
    __syncthreads();
    cur ^= 1;
  }
  #pragma unroll
  for (int mt = 0; mt < 4; ++mt){
    const int rl = wm + mt*16 + quad*4;
    #pragma unroll
    for (int nt = 0; nt < NT; ++nt){
      const int col = n0 + wn + nt*16 + l16;
      float bv = bias ? bf2f(bias[col]) : 0.f;
      #pragma unroll
      for (int r = 0; r < 4; ++r){
        int row = m0 + rl + r;
        if (row < M){
          float v = acc[mt][nt][r] + bv;
          if (res) v += resf32 ? ((const float*)res)[(long)row*ldr + col]
                               : bf2f(((const u16*)res)[(long)row*ldr + col]);
          if (outf32) ((float*)C)[(long)row*ldc + col] = v;
          else        ((u16*)C) [(long)row*ldc + col] = f2bf(v);
        }
      }
    }
  }
}

// ---------------- fused GEGLU GEMM, 128x64 tile ----------------------------
__global__ __launch_bounds__(256) void gemm_geglu(
    const u16* __restrict__ A, const u16* __restrict__ W, u16* __restrict__ C,
    const u16* __restrict__ bias)
{
  __shared__ __align__(16) u16 sA[2][8*512];
  __shared__ __align__(16) u16 sH[2][4*512];
  __shared__ __align__(16) u16 sG[2][4*512];
  const int tid  = threadIdx.x;
  const int wave = tid >> 6, lane = tid & 63;
  const int quad = lane >> 4, l16 = lane & 15;
  const int m0 = blockIdx.y * 128, n0 = blockIdx.x * 64;
  const int wm = (wave >> 1) * 64, wn = (wave & 1) * 32;
  const int srow = lane & 15;
  const int scol = (lane >> 4) * 8;

  long aoff[2];
  #pragma unroll
  for (int i = 0; i < 2; ++i)
    aoff[i] = (long)(m0 + (wave*2 + i)*16 + srow)*DIM + scol;
  const long hoff = (long)(n0 + wave*16 + srow)*DIM + scol;
  const long goff = (long)(FFI + n0 + wave*16 + srow)*DIM + scol;

  f32x4 ah[4][2] = {}, ag[4][2] = {};
  #pragma unroll
  for (int i = 0; i < 2; ++i) gl2lds16(&A[aoff[i]], &sA[0][(wave*2 + i)*512]);
  gl2lds16(&W[hoff], &sH[0][wave*512]);
  gl2lds16(&W[goff], &sG[0][wave*512]);
  __syncthreads();

  int cur = 0;
  for (int k0 = 0; ; ){
    const int kn = k0 + 32;
    if (kn < DIM){
      #pragma unroll
      for (int i = 0; i < 2; ++i) gl2lds16(&A[aoff[i] + kn], &sA[cur^1][(wave*2 + i)*512]);
      gl2lds16(&W[hoff + kn], &sH[cur^1][wave*512]);
      gl2lds16(&W[goff + kn], &sG[cur^1][wave*512]);
    }
    bf8 a[4];
    #pragma unroll
    for (int mt = 0; mt < 4; ++mt) a[mt] = *(const bf8*)&sA[cur][((wm>>4) + mt)*512 + lane*8];
    #pragma unroll
    for (int nt = 0; nt < 2; ++nt){
      bf8 bh = *(const bf8*)&sH[cur][((wn>>4) + nt)*512 + lane*8];
      bf8 bg = *(const bf8*)&sG[cur][((wn>>4) + nt)*512 + lane*8];
      #pragma unroll
      for (int mt = 0; mt < 4; ++mt){
        ah[mt][nt] = __builtin_amdgcn_mfma_f32_16x16x32_bf16(a[mt], bh, ah[mt][nt], 0, 0, 0);
        ag[mt][nt] = __builtin_amdgcn_mfma_f32_16x16x32_bf16(a[mt], bg, ag[mt][nt], 0, 0, 0);
      }
    }
    k0 = kn;
    if (k0 >= DIM) break;
    __syncthreads();
    cur ^= 1;
  }
  #pragma unroll
  for (int mt = 0; mt < 4; ++mt){
    const int rl = wm + mt*16 + quad*4;
    #pragma unroll
    for (int nt = 0; nt < 2; ++nt){
      const int col = n0 + wn + nt*16 + l16;
      const float bh = bf2f(bias[col]);
      const float bg = bf2f(bias[FFI + col]);
      #pragma unroll
      for (int r = 0; r < 4; ++r){
        int row = m0 + rl + r;
        float h = ah[mt][nt][r] + bh;
        float g = ag[mt][nt][r] + bg;
        C[(long)row*FFI + col] = f2bf(h * gelu_t(g));
      }
    }
  }
}

// ---------------- MFMA flash attention, swapped-QK^T -----------------------
// K/V staged via global_load_lds into MFMA-native lane-linear chunks
// (conflict-free frag reads, no staging registers). SINGLE buffer, two
// barriers per chunk with explicit vmcnt(0) drain: conservative, race-free.
template<int MODE>
__global__ __launch_bounds__(256) void attn_k(
    const u16* __restrict__ qbuf, const u16* __restrict__ kbuf,
    const u16* __restrict__ vT, u16* __restrict__ out,
    const u16* __restrict__ zblk)
{
  constexpr int QLD  = MODE ? DIM      : 3*DIM;
  constexpr int KLD  = MODE ? 2*DIM    : 3*DIM;
  constexpr int KCOL = MODE ? 0        : DIM;
  constexpr int VLD  = MODE ? DIM      : TOK;
  constexpr int NK   = MODE ? 77       : 2*SEQ;
  constexpr int NCH  = MODE ? 3        : 64;
  constexpr float C1   = SCALE * 1.4426950408889634f;   // scale * log2(e)
  constexpr float THRR = 8.0f / C1;                     // defer-max threshold

  const int qt = blockIdx.x, h = blockIdx.y, g = blockIdx.z;
  const int tid = threadIdx.x, wave = tid >> 6, lane = tid & 63;
  const int quad = lane >> 4, l16 = lane & 15;

  __shared__ __align__(16) u16 Qs[64*104];
  __shared__ __align__(16) u16 Kb[6*512];   // 2 key-groups x 3 k-slices
  __shared__ __align__(16) u16 Vb[5*512];   // 5 d-groups x 32 keys
  __shared__ __align__(16) u16 Ps[4][16*40];

  const int qrow0 = g*SEQ + qt*64;
  // ---- stage Q (once) + zero pads ----
  for (int v = tid; v < 640; v += 256){
    int r = v/10, c8 = (v - r*10)*8;
    *(U4*)&Qs[r*104 + c8] = *(const U4*)&qbuf[(long)(qrow0 + r)*QLD + h*HD + c8];
  }
  for (int v = tid; v < 128; v += 256){
    U4 z = {0,0,0,0};
    *(U4*)&Qs[(v>>1)*104 + 80 + (v&1)*8] = z;
  }
  __syncthreads();

  bf8 qf[3];
  #pragma unroll
  for (int ks = 0; ks < 3; ++ks)
    qf[ks] = *(const bf8*)&Qs[(wave*16 + l16)*104 + ks*32 + quad*8];

  const int former = (g == 0) ? 0 : (g - 1);

  // stage chunk c: 6 K chunks + 5 V chunks distributed across 4 waves
  auto stage = [&](int c){
    int krow0, vrow0;
    if (MODE == 0){
      int kb = c*32;
      int fr = (kb >> 10) ? former : 0;
      krow0 = fr*SEQ + (kb & (SEQ-1));
      vrow0 = krow0;
    } else {
      krow0 = c*32;                 // key index base within group
      vrow0 = g*80 + c*32;
    }
    #pragma unroll
    for (int ci = 0; ci < 6; ++ci){
      if ((ci & 3) == wave){
        const int ck = ci / 3, ks = ci % 3;
        const int d  = ks*32 + quad*8;          // 0..88
        const int rl = ck*16 + l16;
        const u16* src;
        if (MODE == 0){
          src = (d < HD) ? &kbuf[(long)(krow0 + rl)*KLD + KCOL + h*HD + d] : zblk;
        } else {
          int j = krow0 + rl; j = j < NK ? j : NK-1;
          src = (d < HD) ? &kbuf[((long)g*77 + j)*KLD + KCOL + h*HD + d] : zblk;
        }
        gl2lds16(src, &Kb[ci*512]);
      }
    }
    #pragma unroll
    for (int vi = 0; vi < 5; ++vi){
      if (((vi + 2) & 3) == wave){
        const int dd = vi*16 + l16;
        const u16* src;
        if (MODE == 0){
          src = &vT[(long)(h*HD + dd)*VLD + vrow0 + quad*8];
        } else {
          int key = c*32 + quad*8;              // 0..88 within 80-padded group
          src = (key < 80) ? &vT[(long)(h*HD + dd)*VLD + vrow0 + quad*8] : zblk;
        }
        gl2lds16(src, &Vb[vi*512]);
      }
    }
  };

  f32x4 o[5] = {};
  float mrun = -1e30f, lrun = 0.f, nmc = 0.f;

  for (int c = 0; c < NCH; ++c){
    stage(c);
    asm volatile("s_waitcnt vmcnt(0)" ::: "memory");
    __syncthreads();               // chunk fully staged, visible to all waves

    f32x4 s0 = {}, s1 = {};
    #pragma unroll
    for (int ks = 0; ks < 3; ++ks){
      bf8 kf0 = *(const bf8*)&Kb[ks*512     + lane*8];
      bf8 kf1 = *(const bf8*)&Kb[(3+ks)*512 + lane*8];
      s0 = __builtin_amdgcn_mfma_f32_16x16x32_bf16(kf0, qf[ks], s0, 0, 0, 0);
      s1 = __builtin_amdgcn_mfma_f32_16x16x32_bf16(kf1, qf[ks], s1, 0, 0, 0);
    }

    const int kbase = c*32;
    if (MODE == 1){
      const int kg = kbase + quad*4;
      #pragma unroll
      for (int r = 0; r < 4; ++r){
        if (kg + r >= NK)      s0[r] = -1e30f;
        if (kg + 16 + r >= NK) s1[r] = -1e30f;
      }
    }
    float mxs = fmaxf(fmaxf(fmaxf(s0[0],s0[1]), fmaxf(s0[2],s0[3])),
                      fmaxf(fmaxf(s1[0],s1[1]), fmaxf(s1[2],s1[3])));
    mxs = fmaxf(mxs, __shfl_xor(mxs, 16, 64));
    mxs = fmaxf(mxs, __shfl_xor(mxs, 32, 64));
    if (!__all(mxs - mrun <= THRR)){
      float mn = fmaxf(mrun, mxs);
      float al = exp2f((mrun - mn)*C1);
      mrun = mn; nmc = -mrun*C1;
      lrun *= al;
      float a0 = __shfl(al, quad*4 + 0, 16);
      float a1 = __shfl(al, quad*4 + 1, 16);
      float a2 = __shfl(al, quad*4 + 2, 16);
      float a3 = __shfl(al, quad*4 + 3, 16);
      #pragma unroll
      for (int dt = 0; dt < 5; ++dt){
        o[dt][0] *= a0; o[dt][1] *= a1; o[dt][2] *= a2; o[dt][3] *= a3;
      }
    }
    #pragma unroll
    for (int r = 0; r < 4; ++r){
      s0[r] = exp2f(__builtin_fmaf(s0[r], C1, nmc));
      s1[r] = exp2f(__builtin_fmaf(s1[r], C1, nmc));
    }
    float rs = ((s0[0]+s0[1])+(s0[2]+s0[3])) + ((s1[0]+s1[1])+(s1[2]+s1[3]));
    rs += __shfl_xor(rs, 16, 64);
    rs += __shfl_xor(rs, 32, 64);
    lrun += rs;

    U2 w01, w23;
    w01.x = cvtpk_bf16(s0[0], s0[1]);  w01.y = cvtpk_bf16(s0[2], s0[3]);
    w23.x = cvtpk_bf16(s1[0], s1[1]);  w23.y = cvtpk_bf16(s1[2], s1[3]);
    U2* pr = (U2*)&Ps[wave][l16*40];
    pr[quad]     = w01;
    pr[4 + quad] = w23;
    asm volatile("s_waitcnt lgkmcnt(0)" ::: "memory");
    __builtin_amdgcn_sched_barrier(0);
    bf8 pf = *(const bf8*)&Ps[wave][l16*40 + quad*8];
    #pragma unroll
    for (int dt = 0; dt < 5; ++dt){
      bf8 vf = *(const bf8*)&Vb[dt*512 + lane*8];
      o[dt] = __builtin_amdgcn_mfma_f32_16x16x32_bf16(pf, vf, o[dt], 0, 0, 0);
    }
    __syncthreads();               // all reads done before next stage
  }

  float linv[4];
  #pragma unroll
  for (int r = 0; r < 4; ++r)
    linv[r] = __builtin_amdgcn_rcpf(__shfl(lrun, quad*4 + r, 16));
  const int orow0 = qrow0 + wave*16 + quad*4;
  #pragma unroll
  for (int dt = 0; dt < 5; ++dt){
    const int col = h*HD + dt*16 + l16;
    #pragma unroll
    for (int r = 0; r < 4; ++r)
      out[(long)(orow0 + r)*DIM + col] = f2bf(o[dt][r] * linv[r]);
  }
}

// ---------------- host orchestration ---------------------------------------
extern "C" void kernel_launch(void* const* d_in, const int* in_sizes, int n_in,
                              void* d_out, int out_size, void* d_ws, size_t ws_size,
                              hipStream_t stream)
{
  const float* hidden = (const float*)d_in[0];
  const float* enc    = (const float*)d_in[1];
  const float* ln1w = (const float*)d_in[3],  *ln1b = (const float*)d_in[4];
  const float* q1   = (const float*)d_in[5],  *k1   = (const float*)d_in[6];
  const float* v1   = (const float*)d_in[7],  *o1w  = (const float*)d_in[8];
  const float* o1b  = (const float*)d_in[9];
  const float* ln2w = (const float*)d_in[10], *ln2b = (const float*)d_in[11];
  const float* q2   = (const float*)d_in[12], *k2   = (const float*)d_in[13];
  const float* v2   = (const float*)d_in[14], *o2w  = (const float*)d_in[15];
  const float* o2b  = (const float*)d_in[16];
  const float* ln3w = (const float*)d_in[17], *ln3b = (const float*)d_in[18];
  const float* fw1  = (const float*)d_in[19], *fb1  = (const float*)d_in[20];
  const float* fw2  = (const float*)d_in[21], *fb2  = (const float*)d_in[22];

  u16* ws = (u16*)d_ws;
  u16* Wqkv1T = ws;                           // 1920*640
  u16* o1T    = Wqkv1T + 1920*640;            // 640*640
  u16* q2T    = o1T    + 640*640;
  u16* Wkv2T  = q2T    + 640*640;             // 1280*768
  u16* o2T    = Wkv2T  + 1280*768;
  u16* W1T    = o2T    + 640*640;             // 5120*640
  u16* W2T    = W1T    + 5120*640;            // 640*2560
  u16* xbuf   = W2T    + 640*2560;            // 8192*640
  u16* qkv1   = xbuf   + (size_t)TOK*DIM;     // 8192*1920
  u16* v1T    = qkv1   + (size_t)TOK*3*DIM;   // 640*8192
  u16* ffin   = qkv1;                         // alias: 8192*2560 == qkv1+v1T
  u16* attnb  = v1T    + (size_t)DIM*TOK;     // 8192*640
  u16* hid2   = attnb  + (size_t)TOK*DIM;
  u16* hid3   = hid2   + (size_t)TOK*DIM;
  u16* q2buf  = hid3   + (size_t)TOK*DIM;
  u16* kv2    = q2buf  + (size_t)TOK*DIM;     // 616*1280
  u16* v2T    = kv2    + (size_t)ETOK*2*DIM;  // 640*640 + pad
  u16* encm   = v2T    + 640*640 + 64;        // 616*768
  u16* bln1w  = encm   + (size_t)ETOK*CROSS;
  u16* bln1b  = bln1w + DIM;
  u16* bo1b   = bln1b + DIM;
  u16* bln2w  = bo1b  + DIM;
  u16* bln2b  = bln2w + DIM;
  u16* bo2b   = bln2b + DIM;
  u16* bln3w  = bo2b  + DIM;
  u16* bln3b  = bln3w + DIM;
  u16* bfb2   = bln3b + DIM;
  u16* bfb1   = bfb2  + DIM;                  // 5120
  u16* zblk   = bfb1  + 2*FFI;                // 64 u16 of zeros (16B aligned)
  u16* wsend  = zblk  + 64;
  const size_t needed = ((size_t)(wsend - ws) + 64) * 2;
  if (ws_size < needed) return;

  dim3 blk(256);
  zero_k<<<1, 64, 0, stream>>>(zblk);

  // ---- stage 0: bf16 mirrors of fp32 inputs ----
  CvtJobs jobs;
  jobs.j[0]  = { enc,  encm,  ETOK*CROSS };
  jobs.j[1]  = { ln1w, bln1w, DIM };
  jobs.j[2]  = { ln1b, bln1b, DIM };
  jobs.j[3]  = { o1b,  bo1b,  DIM };
  jobs.j[4]  = { ln2w, bln2w, DIM };
  jobs.j[5]  = { ln2b, bln2b, DIM };
  jobs.j[6]  = { o2b,  bo2b,  DIM };
  jobs.j[7]  = { ln3w, bln3w, DIM };
  jobs.j[8]  = { ln3b, bln3b, DIM };
  jobs.j[9]  = { fb2,  bfb2,  DIM };
  jobs.j[10] = { fb1,  bfb1,  2*FFI };
  cvt_all<<<dim3(64,11), blk, 0, stream>>>(jobs);

  // ---- fused weight transposes into B^T layouts (tiled, all dims %64==0) --
  TJobs tj;
  tj.j[0] = { q1,  Wqkv1T,            640, 640,  640,  640 };
  tj.j[1] = { k1,  Wqkv1T + 640*640,  640, 640,  640,  640 };
  tj.j[2] = { v1,  Wqkv1T + 1280*640, 640, 640,  640,  640 };
  tj.j[3] = { o1w, o1T,               640, 640,  640,  640 };
  tj.j[4] = { q2,  q2T,               640, 640,  640,  640 };
  tj.j[5] = { k2,  Wkv2T,             768, 640,  640,  768 };
  tj.j[6] = { v2,  Wkv2T + 640*768,   768, 640,  640,  768 };
  tj.j[7] = { o2w, o2T,               640, 640,  640,  640 };
  tj.j[8] = { fw1, W1T,               640, 5120, 5120, 640 };
  tj.j[9] = { fw2, W2T,               2560,640,  640,  2560 };
  transpose_tiled<<<dim3(800,10), blk, 0, stream>>>(tj);

  // ---- block 1: LN1(fp32) -> qkv -> temporal attention -> o1 + res(fp32) ----
  ln_k<<<TOK, blk, 0, stream>>>(hidden, bln1w, bln1b, xbuf, 1);
  gemm_bt<128><<<dim3(15,64), blk, 0, stream>>>(xbuf, Wqkv1T, qkv1,
      TOK, 3*DIM, DIM, DIM, DIM, 3*DIM, nullptr, nullptr, 0, 0, 0);
  transpose_tile<<<dim3(10,128), blk, 0, stream>>>(qkv1 + 2*DIM, v1T, 3*DIM, TOK);
  attn_k<0><<<dim3(16,8,8), blk, 0, stream>>>(qkv1, qkv1, v1T, attnb, zblk);
  gemm_bt<64><<<dim3(10,64), blk, 0, stream>>>(attnb, o1T, hid2,
      TOK, DIM, DIM, DIM, DIM, DIM, bo1b, hidden, DIM, 1, 0);

  // ---- block 2: LN2 -> q2 / kv2 -> cross attention -> o2 + residual ----
  ln_k<<<TOK, blk, 0, stream>>>(hid2, bln2w, bln2b, xbuf, 0);
  gemm_bt<64><<<dim3(10,64), blk, 0, stream>>>(xbuf, q2T, q2buf,
      TOK, DIM, DIM, DIM, DIM, DIM, nullptr, nullptr, 0, 0, 0);
  gemm_bt<64><<<dim3(20,5), blk, 0, stream>>>(encm, Wkv2T, kv2,
      ETOK, 2*DIM, CROSS, CROSS, CROSS, 2*DIM, nullptr, nullptr, 0, 0, 0);
  transpose_v2<<<dim3((DIM*640 + 255)/256), blk, 0, stream>>>(kv2, v2T);
  attn_k<1><<<dim3(16,8,8), blk, 0, stream>>>(q2buf, kv2, v2T, attnb, zblk);
  gemm_bt<64><<<dim3(10,64), blk, 0, stream>>>(attnb, o2T, hid3,
      TOK, DIM, DIM, DIM, DIM, DIM, bo2b, hid2, DIM, 0, 0);

  // ---- block 3: LN3 -> GEGLU FF -> out(fp32) + residual ----
  ln_k<<<TOK, blk, 0, stream>>>(hid3, bln3w, bln3b, xbuf, 0);
  gemm_geglu<<<dim3(40,64), blk, 0, stream>>>(xbuf, W1T, ffin, bfb1);
  gemm_bt<64><<<dim3(10,64), blk, 0, stream>>>(ffin, W2T, d_out,
      TOK, DIM, FFI, FFI, FFI, DIM, bfb2, hid3, DIM, 0, 1);
}